// Round 4
// baseline (381.980 us; speedup 1.0000x reference)
//
#include <hip/hip_runtime.h>

#define NREL 3
#define BSH 9              // 512 nodes per dst bucket
#define BNODES 512
#define NBLK_A 256         // blocks in hist/place passes
#define TS 14              // src tile = 16384 nodes = 2 MB of h1
#define NTMAX 8

typedef __attribute__((ext_vector_type(8))) short short8;
typedef __attribute__((ext_vector_type(4))) float floatx4;

static __device__ inline float bf2f(unsigned short u) {
    union { unsigned int i; float f; } v; v.i = ((unsigned int)u) << 16; return v.f;
}
static __device__ inline unsigned short f2bf(float f) {
    union { float f; unsigned int i; } v; v.f = f;
    unsigned int x = v.i;
    return (unsigned short)((x + 0x7FFF + ((x >> 16) & 1)) >> 16);  // RNE
}

// ---------------------------------------------------------------------------
// K1: per-combo tables. x1tab[64][32], root1t[64][64] (= x1@root1 + b1)
// ---------------------------------------------------------------------------
__global__ void build_tables(const float* __restrict__ pre_w, const float* __restrict__ pre_b,
                             const float* __restrict__ root1, const float* __restrict__ b1,
                             float* __restrict__ x1tab, float* __restrict__ root1t) {
    int combo = blockIdx.x, j = threadIdx.x;
    __shared__ float x1s[32];
    int s = combo >> 3, c = combo & 7;
    if (j < 32) {
        float v = pre_w[s * 32 + j] + pre_w[(8 + c) * 32 + j] + pre_b[j];
        v = v > 0.f ? v : 0.f;
        x1s[j] = v;
        x1tab[combo * 32 + j] = v;
    }
    __syncthreads();
    float acc = b1[j];
#pragma unroll
    for (int k = 0; k < 32; ++k) acc = fmaf(x1s[k], root1[k * 64 + j], acc);
    root1t[combo * 64 + j] = acc;
}

// ---------------------------------------------------------------------------
// K2: pre-shuffle weights into MFMA B-fragment layout (bf16).
// ---------------------------------------------------------------------------
__global__ void prep_B(const float* __restrict__ w1, const float* __restrict__ root2,
                       const float* __restrict__ w2,
                       unsigned short* __restrict__ B1f, unsigned short* __restrict__ B2f) {
    int t = blockIdx.x * blockDim.x + threadIdx.x;
    if (t < 4 * 8 * 64 * 8) {
        int i = t & 7, l = (t >> 3) & 63, kt = (t >> 9) & 7, nt = t >> 12;
        int k = kt * 32 + ((l >> 4) * 8) + i;
        int col = nt * 16 + (l & 15);
        float v = (k < 64) ? root2[k * 64 + col] : w2[(k - 64) * 64 + col];
        B2f[t] = f2bf(v);
    }
    if (t < 4 * 3 * 64 * 8) {
        int i = t & 7, l = (t >> 3) & 63;
        int rest = t >> 9;
        int kt = rest % 3, nt = rest / 3;
        int k = kt * 32 + ((l >> 4) * 8) + i;
        int col = nt * 16 + (l & 15);
        B1f[t] = f2bf(w1[k * 64 + col]);
    }
}

// K3: combo[i] as u8
__global__ void combo_kernel(const int* __restrict__ node_x, unsigned char* __restrict__ combo, int N) {
    int i = blockIdx.x * blockDim.x + threadIdx.x;
    if (i < N) combo[i] = (unsigned char)(node_x[2 * i] * 8 + node_x[2 * i + 1]);
}

// ---------------------------------------------------------------------------
// K4 (pass A0): per-block dst-bucket histogram. hist[b*NBLK_A + blk]
// ---------------------------------------------------------------------------
__global__ void __launch_bounds__(256) hist_kernel(const int* __restrict__ ei,
                                                   int* __restrict__ hist, int E, int NB, int chunk) {
    __shared__ int lh[256];
    for (int t = threadIdx.x; t < NB; t += 256) lh[t] = 0;
    __syncthreads();
    int s = blockIdx.x * chunk, e1 = min(E, s + chunk);
    for (int e = s + threadIdx.x; e < e1; e += 256)
        atomicAdd(&lh[ei[E + e] >> BSH], 1);
    __syncthreads();
    for (int b = threadIdx.x; b < NB; b += 256) hist[b * NBLK_A + blockIdx.x] = lh[b];
}

// generic exclusive scan (3 kernels)
__global__ void scan1(const int* __restrict__ in, int* __restrict__ out,
                      int* __restrict__ bsums, int n) {
    __shared__ int s[1024];
    int i = blockIdx.x * 1024 + threadIdx.x;
    int d = (i < n) ? in[i] : 0;
    s[threadIdx.x] = d;
    __syncthreads();
    for (int off = 1; off < 1024; off <<= 1) {
        int v = (threadIdx.x >= off) ? s[threadIdx.x - off] : 0;
        __syncthreads();
        s[threadIdx.x] += v;
        __syncthreads();
    }
    if (i < n) out[i] = s[threadIdx.x] - d;
    if (threadIdx.x == 1023) bsums[blockIdx.x] = s[1023];
}
__global__ void scan2(int* __restrict__ bsums, int nb) {
    __shared__ int s[128];
    int v = (threadIdx.x < nb) ? bsums[threadIdx.x] : 0;
    s[threadIdx.x] = v;
    __syncthreads();
    for (int off = 1; off < 128; off <<= 1) {
        int u = (threadIdx.x >= off) ? s[threadIdx.x - off] : 0;
        __syncthreads();
        s[threadIdx.x] += u;
        __syncthreads();
    }
    if (threadIdx.x < nb) bsums[threadIdx.x] = s[threadIdx.x] - v;
}
__global__ void scan3(int* __restrict__ out, const int* __restrict__ bsums, int n) {
    int i = blockIdx.x * 1024 + threadIdx.x;
    if (i < n) out[i] += bsums[blockIdx.x];
}

// ---------------------------------------------------------------------------
// K5 (pass A1): place edges into dst-buckets. staged = dloc<<19 | rel<<17 | src
// ---------------------------------------------------------------------------
__global__ void __launch_bounds__(256) place_kernel(const int* __restrict__ ei, const int* __restrict__ et,
                                                    const int* __restrict__ off, unsigned* __restrict__ staged,
                                                    int E, int NB, int chunk) {
    __shared__ int lh[256];
    for (int t = threadIdx.x; t < NB; t += 256) lh[t] = 0;
    __syncthreads();
    int s = blockIdx.x * chunk, e1 = min(E, s + chunk);
    for (int e = s + threadIdx.x; e < e1; e += 256) {
        int d = ei[E + e];
        int b = d >> BSH;
        int lr = atomicAdd(&lh[b], 1);
        int pos = off[b * NBLK_A + blockIdx.x] + lr;
        staged[pos] = ((unsigned)(d & (BNODES - 1)) << 19) | ((unsigned)et[e] << 17) | (unsigned)ei[e];
    }
}

// ---------------------------------------------------------------------------
// K6 (pass B): per-bucket finalize. Sort edges by (dst, srcTile); emit
//   edges[e] = rel<<23 | combo(src)<<17 | src
//   baseT[i*NT + t] = start of (node i, tile t) span (+ sentinel at N*NT)
//   cnt3[i] = packed per-rel in-degree counts (10 bits each)
// ---------------------------------------------------------------------------
__global__ void __launch_bounds__(256) finalize_kernel(
        const unsigned* __restrict__ staged, const int* __restrict__ off,
        const unsigned char* __restrict__ combo, unsigned* __restrict__ edges,
        int* __restrict__ baseT, unsigned* __restrict__ cnt3,
        int E, int N, int NB, int NT) {
    __shared__ int lcnt[BNODES * NTMAX];
    __shared__ int lrel[BNODES * 3];
    __shared__ int part[256];
    int blk = blockIdx.x;
    int d0 = blk * BNODES;
    int nn = min(BNODES, N - d0);
    int estart = off[blk * NBLK_A];
    int eend = (blk == NB - 1) ? E : off[(blk + 1) * NBLK_A];
    int C = BNODES * NT;
    for (int t = threadIdx.x; t < C; t += 256) lcnt[t] = 0;
    for (int t = threadIdx.x; t < BNODES * 3; t += 256) lrel[t] = 0;
    __syncthreads();
    for (int e = estart + threadIdx.x; e < eend; e += 256) {
        unsigned p = staged[e];
        int dloc = p >> 19, src = p & 0x1FFFF;
        atomicAdd(&lcnt[dloc * NT + (src >> TS)], 1);
        atomicAdd(&lrel[dloc * 3 + ((p >> 17) & 3)], 1);
    }
    __syncthreads();
    int t = threadIdx.x;
    int per = (C + 255) >> 8;
    int i0 = t * per, i1 = min(i0 + per, C);
    int sum = 0;
    for (int i = i0; i < i1; ++i) sum += lcnt[i];
    part[t] = sum;
    __syncthreads();
    for (int o = 1; o < 256; o <<= 1) {
        int u = (t >= o) ? part[t - o] : 0;
        __syncthreads();
        part[t] += u;
        __syncthreads();
    }
    int run = estart + part[t] - sum;
    for (int i = i0; i < i1; ++i) { int v = lcnt[i]; lcnt[i] = run; run += v; }
    __syncthreads();
    for (int idx = threadIdx.x; idx < nn * NT; idx += 256)
        baseT[(size_t)d0 * NT + idx] = lcnt[idx];
    for (int j = threadIdx.x; j < nn; j += 256) {
        unsigned c0 = lrel[j * 3], c1 = lrel[j * 3 + 1], c2 = lrel[j * 3 + 2];
        cnt3[d0 + j] = c0 | (c1 << 10) | (c2 << 20);
    }
    if (blk == NB - 1 && threadIdx.x == 0) baseT[(size_t)N * NT] = E;
    __syncthreads();
    for (int e = estart + threadIdx.x; e < eend; e += 256) {
        unsigned p = staged[e];
        int dloc = p >> 19, src = p & 0x1FFFF;
        int slot = atomicAdd(&lcnt[dloc * NT + (src >> TS)], 1);
        edges[slot] = (((p >> 17) & 3u) << 23) | ((unsigned)combo[src] << 17) | (unsigned)src;
    }
}

// ---------------------------------------------------------------------------
// K7: fused conv1 (agg from LDS table + MFMA transform) -> h1 bf16
// Block = 64 nodes, 4 waves x 16 nodes each.
// ---------------------------------------------------------------------------
__global__ void __launch_bounds__(256) conv1_fused(
        const unsigned* __restrict__ edges, const int* __restrict__ baseT,
        const unsigned* __restrict__ cnt3, const float* __restrict__ x1tab,
        const float* __restrict__ root1t, const unsigned char* __restrict__ combo,
        const unsigned short* __restrict__ B1f, unsigned short* __restrict__ h1,
        int N, int NT) {
    __shared__ float tab[64 * 32];
    __shared__ unsigned short aggb[64][104];   // 104-pad: 208B row stride, 2-way banks
    for (int t = threadIdx.x; t < 64 * 32; t += 256) tab[t] = x1tab[t];
    __syncthreads();
    int g0 = blockIdx.x * 64;
    int w = threadIdx.x >> 6, lane = threadIdx.x & 63;
    int k = lane & 31, half = lane >> 5;
    for (int n = 16 * w; n < 16 * w + 16; ++n) {
        int node = g0 + n;
        if (node >= N) break;
        int s = baseT[(size_t)node * NT], e1 = baseT[(size_t)(node + 1) * NT];
        float a0 = 0.f, a1 = 0.f, a2 = 0.f;
        for (int e = s + half; e < e1; e += 2) {
            unsigned p = edges[e];
            int c = (p >> 17) & 63, r = p >> 23;
            float v = tab[c * 32 + k];
            a0 += (r == 0) ? v : 0.f;
            a1 += (r == 1) ? v : 0.f;
            a2 += (r == 2) ? v : 0.f;
        }
        a0 += __shfl_xor(a0, 32);
        a1 += __shfl_xor(a1, 32);
        a2 += __shfl_xor(a2, 32);
        if (half == 0) {
            unsigned c3 = cnt3[node];
            unsigned c0 = c3 & 1023, c1 = (c3 >> 10) & 1023, c2 = c3 >> 20;
            aggb[n][k]      = f2bf(a0 * (c0 ? 1.f / (float)c0 : 0.f));
            aggb[n][32 + k] = f2bf(a1 * (c1 ? 1.f / (float)c1 : 0.f));
            aggb[n][64 + k] = f2bf(a2 * (c2 ? 1.f / (float)c2 : 0.f));
        }
    }
    __syncthreads();
    int n0 = g0 + 16 * w;
    if (n0 >= N) return;
    int m = lane & 15, kg = lane >> 4;
    short8 a[3];
#pragma unroll
    for (int kt = 0; kt < 3; ++kt)
        a[kt] = *(const short8*)&aggb[16 * w + m][kt * 32 + kg * 8];
#pragma unroll
    for (int nt = 0; nt < 4; ++nt) {
        floatx4 c = {0.f, 0.f, 0.f, 0.f};
#pragma unroll
        for (int kt = 0; kt < 3; ++kt) {
            short8 b = *(const short8*)(B1f + ((nt * 3 + kt) * 64 + lane) * 8);
            c = __builtin_amdgcn_mfma_f32_16x16x32_bf16(a[kt], b, c, 0, 0, 0);
        }
#pragma unroll
        for (int q = 0; q < 4; ++q) {
            int node = n0 + kg * 4 + q;
            if (node < N) {
                float v = c[q] + root1t[(int)combo[node] * 64 + nt * 16 + m];
                v = v > 0.f ? v : 0.f;
                h1[(size_t)node * 64 + nt * 16 + m] = f2bf(v);
            }
        }
    }
}

// ---------------------------------------------------------------------------
// K8: fused conv2: src-tile-phased gather (reg acc) + MFMA + pooled atomics.
// Block = 64 nodes; each wave owns 16 nodes, acc in 48 fp32 regs/lane.
// ---------------------------------------------------------------------------
__global__ void __launch_bounds__(256) conv2_fused(
        const unsigned* __restrict__ edges, const int* __restrict__ baseT,
        const unsigned* __restrict__ cnt3, const unsigned short* __restrict__ h1,
        const unsigned short* __restrict__ B2f, const float* __restrict__ b2,
        const int* __restrict__ batch, float* __restrict__ pooled, int N, int NT) {
    __shared__ unsigned short aggb[64][200];   // 400B row stride, 2-way banks
    __shared__ int bl[64 * NTMAX + 1];
    int g0 = blockIdx.x * 64;
    int nn = min(64, N - g0);
    for (int j = threadIdx.x; j <= nn * NT; j += 256) bl[j] = baseT[(size_t)g0 * NT + j];
    __syncthreads();
    int w = threadIdx.x >> 6, lane = threadIdx.x & 63;
    int nw0 = 16 * w;
    bool active = (g0 + nw0) < N;
    float a0[16], a1[16], a2[16];
#pragma unroll
    for (int n = 0; n < 16; ++n) { a0[n] = 0.f; a1[n] = 0.f; a2[n] = 0.f; }
    if (active) {
        for (int t = 0; t < NT; ++t) {
#pragma unroll
            for (int n = 0; n < 16; ++n) {
                int s = bl[(nw0 + n) * NT + t], e1 = bl[(nw0 + n) * NT + t + 1];
                int e = s;
                for (; e + 1 < e1; e += 2) {
                    unsigned p = edges[e], p2 = edges[e + 1];
                    float v  = bf2f(h1[(size_t)(p & 0x1FFFF) * 64 + lane]);
                    float v2 = bf2f(h1[(size_t)(p2 & 0x1FFFF) * 64 + lane]);
                    int r = p >> 23, r2 = p2 >> 23;
                    a0[n] += (r == 0) ? v : 0.f;
                    a1[n] += (r == 1) ? v : 0.f;
                    a2[n] += (r == 2) ? v : 0.f;
                    a0[n] += (r2 == 0) ? v2 : 0.f;
                    a1[n] += (r2 == 1) ? v2 : 0.f;
                    a2[n] += (r2 == 2) ? v2 : 0.f;
                }
                if (e < e1) {
                    unsigned p = edges[e];
                    float v = bf2f(h1[(size_t)(p & 0x1FFFF) * 64 + lane]);
                    int r = p >> 23;
                    a0[n] += (r == 0) ? v : 0.f;
                    a1[n] += (r == 1) ? v : 0.f;
                    a2[n] += (r == 2) ? v : 0.f;
                }
            }
        }
#pragma unroll
        for (int n = 0; n < 16; ++n) {
            unsigned c3 = cnt3[g0 + nw0 + n];
            unsigned c0 = c3 & 1023, c1 = (c3 >> 10) & 1023, c2 = c3 >> 20;
            aggb[nw0 + n][lane]       = f2bf(a0[n] * (c0 ? 1.f / (float)c0 : 0.f));
            aggb[nw0 + n][64 + lane]  = f2bf(a1[n] * (c1 ? 1.f / (float)c1 : 0.f));
            aggb[nw0 + n][128 + lane] = f2bf(a2[n] * (c2 ? 1.f / (float)c2 : 0.f));
        }
    }
    __syncthreads();
    if (!active) return;
    int m = lane & 15, kg = lane >> 4;
    short8 a[8];
#pragma unroll
    for (int kt = 0; kt < 2; ++kt)
        a[kt] = *(const short8*)(h1 + (size_t)(g0 + nw0 + m) * 64 + kt * 32 + kg * 8);
#pragma unroll
    for (int kt = 2; kt < 8; ++kt)
        a[kt] = *(const short8*)&aggb[nw0 + m][(kt - 2) * 32 + kg * 8];
    int bq[4];
#pragma unroll
    for (int q = 0; q < 4; ++q) {
        int node = g0 + nw0 + kg * 4 + q;
        bq[q] = batch[node < N ? node : N - 1];
    }
#pragma unroll
    for (int nt = 0; nt < 4; ++nt) {
        floatx4 c = {0.f, 0.f, 0.f, 0.f};
#pragma unroll
        for (int kt = 0; kt < 8; ++kt) {
            short8 b = *(const short8*)(B2f + ((nt * 8 + kt) * 64 + lane) * 8);
            c = __builtin_amdgcn_mfma_f32_16x16x32_bf16(a[kt], b, c, 0, 0, 0);
        }
        float bias = b2[nt * 16 + m];
#pragma unroll
        for (int q = 0; q < 4; ++q) {
            int node = g0 + nw0 + kg * 4 + q;
            if (node < N) {
                float v = c[q] + bias;
                v = v > 0.f ? v : 0.f;
                atomicAdd(&pooled[bq[q] * 64 + nt * 16 + m], v);
            }
        }
    }
}

// ---------------------------------------------------------------------------
// K9: classifier from pooled sums; counts via sorted-batch binary search.
// ---------------------------------------------------------------------------
__global__ void __launch_bounds__(64) cls_kernel(
        const float* __restrict__ pooled, const int* __restrict__ batch,
        const float* __restrict__ cls_w, const float* __restrict__ cls_b,
        float* __restrict__ out, int N, int G) {
    int g = blockIdx.x, lane = threadIdx.x;
    auto lb = [&](int key) {
        int lo = 0, hi = N;
        while (lo < hi) { int mid = (lo + hi) >> 1; if (batch[mid] < key) lo = mid + 1; else hi = mid; }
        return lo;
    };
    int cnt = lb(g + 1) - lb(g);
    float p = pooled[g * 64 + lane] / (float)(cnt > 0 ? cnt : 1);
    __shared__ float ps[64];
    ps[lane] = p;
    __syncthreads();
    if (lane < 10) {
        float o = cls_b[lane];
#pragma unroll
        for (int j = 0; j < 64; ++j) o = fmaf(ps[j], cls_w[j * 10 + lane], o);
        out[g * 10 + lane] = o;
    }
}

// ---------------------------------------------------------------------------
extern "C" void kernel_launch(void* const* d_in, const int* in_sizes, int n_in,
                              void* d_out, int out_size, void* d_ws, size_t ws_size,
                              hipStream_t stream) {
    const int*   node_x = (const int*)d_in[0];
    const int*   ei     = (const int*)d_in[1];
    const int*   et     = (const int*)d_in[2];
    const int*   batch  = (const int*)d_in[3];
    const float* pre_w  = (const float*)d_in[4];
    const float* pre_b  = (const float*)d_in[5];
    const float* w1     = (const float*)d_in[6];
    const float* root1  = (const float*)d_in[7];
    const float* b1     = (const float*)d_in[8];
    const float* w2     = (const float*)d_in[9];
    const float* root2  = (const float*)d_in[10];
    const float* b2     = (const float*)d_in[11];
    const float* cls_w  = (const float*)d_in[12];
    const float* cls_b  = (const float*)d_in[13];
    float* out = (float*)d_out;

    int N = in_sizes[0] / 2;
    int E = in_sizes[1] / 2;
    int G = out_size / 10;

    int NB = (N + BNODES - 1) >> BSH;
    int chunk = (E + NBLK_A - 1) / NBLK_A;
    int nh = NB * NBLK_A;
    int nscan = (nh + 1023) / 1024;
    int NT = (N + (1 << TS) - 1) >> TS;    // 7 for N=100000 (<= NTMAX)

    char* ws = (char*)d_ws;
    size_t off_b = 0;
    auto alloc = [&](size_t bytes) {
        void* p = ws + off_b;
        off_b = (off_b + bytes + 255) & ~(size_t)255;
        return p;
    };
    float*          x1tab  = (float*)alloc(64 * 32 * sizeof(float));
    float*          root1t = (float*)alloc(64 * 64 * sizeof(float));
    unsigned short* B1f    = (unsigned short*)alloc(4 * 3 * 64 * 8 * sizeof(short));
    unsigned short* B2f    = (unsigned short*)alloc(4 * 8 * 64 * 8 * sizeof(short));
    unsigned char*  combo  = (unsigned char*)alloc((size_t)N + 64);
    int*            hist   = (int*)alloc((size_t)nh * sizeof(int));
    int*            hoff   = (int*)alloc((size_t)nh * sizeof(int));
    int*            bsums  = (int*)alloc(128 * sizeof(int));
    unsigned*       staged = (unsigned*)alloc((size_t)E * sizeof(unsigned));
    unsigned*       edges  = (unsigned*)alloc((size_t)E * sizeof(unsigned));
    int*            baseT  = (int*)alloc(((size_t)N * NT + 8) * sizeof(int));
    unsigned*       cnt3   = (unsigned*)alloc((size_t)N * sizeof(unsigned));
    unsigned short* h1     = (unsigned short*)alloc((size_t)(N + 16) * 64 * sizeof(short));
    float*          pooled = (float*)alloc((size_t)G * 64 * sizeof(float));

    build_tables<<<64, 64, 0, stream>>>(pre_w, pre_b, root1, b1, x1tab, root1t);
    prep_B<<<64, 256, 0, stream>>>(w1, root2, w2, B1f, B2f);
    combo_kernel<<<(N + 255) / 256, 256, 0, stream>>>(node_x, combo, N);

    hist_kernel<<<NBLK_A, 256, 0, stream>>>(ei, hist, E, NB, chunk);
    scan1<<<nscan, 1024, 0, stream>>>(hist, hoff, bsums, nh);
    scan2<<<1, 128, 0, stream>>>(bsums, nscan);
    scan3<<<nscan, 1024, 0, stream>>>(hoff, bsums, nh);
    place_kernel<<<NBLK_A, 256, 0, stream>>>(ei, et, hoff, staged, E, NB, chunk);
    finalize_kernel<<<NB, 256, 0, stream>>>(staged, hoff, combo, edges, baseT, cnt3, E, N, NB, NT);

    int nblk = (N + 63) / 64;
    conv1_fused<<<nblk, 256, 0, stream>>>(edges, baseT, cnt3, x1tab, root1t, combo, B1f, h1, N, NT);
    hipMemsetAsync(pooled, 0, (size_t)G * 64 * sizeof(float), stream);
    conv2_fused<<<nblk, 256, 0, stream>>>(edges, baseT, cnt3, h1, B2f, b2, batch, pooled, N, NT);
    cls_kernel<<<G, 64, 0, stream>>>(pooled, batch, cls_w, cls_b, out, N, G);
}

// Round 5
// 280.261 us; speedup vs baseline: 1.3629x; 1.3629x over previous
//
#include <hip/hip_runtime.h>

#define NREL 3
#define BSH 9              // 512 nodes per dst bucket
#define BNODES 512
#define NBLK_A 256         // blocks in hist/place passes

typedef __attribute__((ext_vector_type(8))) short short8;
typedef __attribute__((ext_vector_type(4))) float floatx4;

static __device__ inline float bf2f(unsigned short u) {
    union { unsigned int i; float f; } v; v.i = ((unsigned int)u) << 16; return v.f;
}
static __device__ inline unsigned short f2bf(float f) {
    union { float f; unsigned int i; } v; v.f = f;
    unsigned int x = v.i;
    return (unsigned short)((x + 0x7FFF + ((x >> 16) & 1)) >> 16);  // RNE
}
static __device__ inline float asf(unsigned int u) {
    union { unsigned int i; float f; } v; v.i = u; return v.f;
}

// ---------------------------------------------------------------------------
// K1: per-combo tables. x1tab[64][32], root1t[64][64] (= x1@root1 + b1)
// ---------------------------------------------------------------------------
__global__ void build_tables(const float* __restrict__ pre_w, const float* __restrict__ pre_b,
                             const float* __restrict__ root1, const float* __restrict__ b1,
                             float* __restrict__ x1tab, float* __restrict__ root1t) {
    int combo = blockIdx.x, j = threadIdx.x;
    __shared__ float x1s[32];
    int s = combo >> 3, c = combo & 7;
    if (j < 32) {
        float v = pre_w[s * 32 + j] + pre_w[(8 + c) * 32 + j] + pre_b[j];
        v = v > 0.f ? v : 0.f;
        x1s[j] = v;
        x1tab[combo * 32 + j] = v;
    }
    __syncthreads();
    float acc = b1[j];
#pragma unroll
    for (int k = 0; k < 32; ++k) acc = fmaf(x1s[k], root1[k * 64 + j], acc);
    root1t[combo * 64 + j] = acc;
}

// ---------------------------------------------------------------------------
// K2: pre-shuffle weights into MFMA B-fragment layout (bf16).
// ---------------------------------------------------------------------------
__global__ void prep_B(const float* __restrict__ w1, const float* __restrict__ root2,
                       const float* __restrict__ w2,
                       unsigned short* __restrict__ B1f, unsigned short* __restrict__ B2f) {
    int t = blockIdx.x * blockDim.x + threadIdx.x;
    if (t < 4 * 8 * 64 * 8) {
        int i = t & 7, l = (t >> 3) & 63, kt = (t >> 9) & 7, nt = t >> 12;
        int k = kt * 32 + ((l >> 4) * 8) + i;
        int col = nt * 16 + (l & 15);
        float v = (k < 64) ? root2[k * 64 + col] : w2[(k - 64) * 64 + col];
        B2f[t] = f2bf(v);
    }
    if (t < 4 * 3 * 64 * 8) {
        int i = t & 7, l = (t >> 3) & 63;
        int rest = t >> 9;
        int kt = rest % 3, nt = rest / 3;
        int k = kt * 32 + ((l >> 4) * 8) + i;
        int col = nt * 16 + (l & 15);
        B1f[t] = f2bf(w1[k * 64 + col]);
    }
}

// K3: combo[i] as u8
__global__ void combo_kernel(const int* __restrict__ node_x, unsigned char* __restrict__ combo, int N) {
    int i = blockIdx.x * blockDim.x + threadIdx.x;
    if (i < N) combo[i] = (unsigned char)(node_x[2 * i] * 8 + node_x[2 * i + 1]);
}

// ---------------------------------------------------------------------------
// K4 (pass A0): per-block dst-bucket histogram. hist[b*NBLK_A + blk]
// ---------------------------------------------------------------------------
__global__ void __launch_bounds__(256) hist_kernel(const int* __restrict__ ei,
                                                   int* __restrict__ hist, int E, int NB, int chunk) {
    __shared__ int lh[256];
    for (int t = threadIdx.x; t < NB; t += 256) lh[t] = 0;
    __syncthreads();
    int s = blockIdx.x * chunk, e1 = min(E, s + chunk);
    for (int e = s + threadIdx.x; e < e1; e += 256)
        atomicAdd(&lh[ei[E + e] >> BSH], 1);
    __syncthreads();
    for (int b = threadIdx.x; b < NB; b += 256) hist[b * NBLK_A + blockIdx.x] = lh[b];
}

// generic exclusive scan (3 kernels)
__global__ void scan1(const int* __restrict__ in, int* __restrict__ out,
                      int* __restrict__ bsums, int n) {
    __shared__ int s[1024];
    int i = blockIdx.x * 1024 + threadIdx.x;
    int d = (i < n) ? in[i] : 0;
    s[threadIdx.x] = d;
    __syncthreads();
    for (int off = 1; off < 1024; off <<= 1) {
        int v = (threadIdx.x >= off) ? s[threadIdx.x - off] : 0;
        __syncthreads();
        s[threadIdx.x] += v;
        __syncthreads();
    }
    if (i < n) out[i] = s[threadIdx.x] - d;
    if (threadIdx.x == 1023) bsums[blockIdx.x] = s[1023];
}
__global__ void scan2(int* __restrict__ bsums, int nb) {
    __shared__ int s[128];
    int v = (threadIdx.x < nb) ? bsums[threadIdx.x] : 0;
    s[threadIdx.x] = v;
    __syncthreads();
    for (int off = 1; off < 128; off <<= 1) {
        int u = (threadIdx.x >= off) ? s[threadIdx.x - off] : 0;
        __syncthreads();
        s[threadIdx.x] += u;
        __syncthreads();
    }
    if (threadIdx.x < nb) bsums[threadIdx.x] = s[threadIdx.x] - v;
}
__global__ void scan3(int* __restrict__ out, const int* __restrict__ bsums, int n) {
    int i = blockIdx.x * 1024 + threadIdx.x;
    if (i < n) out[i] += bsums[blockIdx.x];
}

// ---------------------------------------------------------------------------
// K5 (pass A1): place edges into dst-buckets. staged = dloc<<19 | rel<<17 | src
// ---------------------------------------------------------------------------
__global__ void __launch_bounds__(256) place_kernel(const int* __restrict__ ei, const int* __restrict__ et,
                                                    const int* __restrict__ off, unsigned* __restrict__ staged,
                                                    int E, int NB, int chunk) {
    __shared__ int lh[256];
    for (int t = threadIdx.x; t < NB; t += 256) lh[t] = 0;
    __syncthreads();
    int s = blockIdx.x * chunk, e1 = min(E, s + chunk);
    for (int e = s + threadIdx.x; e < e1; e += 256) {
        int d = ei[E + e];
        int b = d >> BSH;
        int lr = atomicAdd(&lh[b], 1);
        int pos = off[b * NBLK_A + blockIdx.x] + lr;
        staged[pos] = ((unsigned)(d & (BNODES - 1)) << 19) | ((unsigned)et[e] << 17) | (unsigned)ei[e];
    }
}

// ---------------------------------------------------------------------------
// K6 (pass B): per-bucket finalize into even-padded per-dst CSR.
//   edges2[e] = src*32 | rel<<28      (rel=3 -> dummy)
//   edges1[e] = combo(src)<<2 | rel   (u8)
//   base1[i]  = start of node i's span; plen[i] = padded (even) length
//   cnt3[i]   = packed per-rel true counts (10 bits each)
// Bucket capacity = raw + BNODES, base = off[blk*NBLK_A] + blk*BNODES.
// ---------------------------------------------------------------------------
__global__ void __launch_bounds__(256) finalize_kernel(
        const unsigned* __restrict__ staged, const int* __restrict__ off,
        const unsigned char* __restrict__ combo,
        unsigned char* __restrict__ edges1, unsigned* __restrict__ edges2,
        int* __restrict__ base1, unsigned short* __restrict__ plen,
        unsigned* __restrict__ cnt3, int E, int N, int NB) {
    __shared__ int lcnt[BNODES];        // raw counts -> placement cursors
    __shared__ int lraw[BNODES];
    __shared__ int lrel[BNODES * 3];
    __shared__ int part[256];
    int blk = blockIdx.x;
    int d0 = blk * BNODES;
    int nn = min(BNODES, N - d0);
    int estart = off[blk * NBLK_A];
    int eend = (blk == NB - 1) ? E : off[(blk + 1) * NBLK_A];
    int ebase = estart + blk * BNODES;  // padded-capacity base
    for (int t = threadIdx.x; t < BNODES; t += 256) lcnt[t] = 0;
    for (int t = threadIdx.x; t < BNODES * 3; t += 256) lrel[t] = 0;
    __syncthreads();
    for (int e = estart + threadIdx.x; e < eend; e += 256) {
        unsigned p = staged[e];
        int dloc = p >> 19;
        atomicAdd(&lcnt[dloc], 1);
        atomicAdd(&lrel[dloc * 3 + ((p >> 17) & 3)], 1);
    }
    __syncthreads();
    // padded exclusive scan (2 nodes per thread)
    int t = threadIdx.x;
    int i0 = t * 2;
    int c0 = lcnt[i0], c1 = lcnt[i0 + 1];
    int p0 = (c0 + 1) & ~1, p1 = (c1 + 1) & ~1;
    int sum = p0 + p1;
    part[t] = sum;
    __syncthreads();
    for (int o = 1; o < 256; o <<= 1) {
        int u = (t >= o) ? part[t - o] : 0;
        __syncthreads();
        part[t] += u;
        __syncthreads();
    }
    int run = ebase + part[t] - sum;
    lraw[i0] = c0; lraw[i0 + 1] = c1;
    lcnt[i0] = run; lcnt[i0 + 1] = run + p0;
    if (i0 < nn)     { base1[d0 + i0] = run;          plen[d0 + i0] = (unsigned short)p0; }
    if (i0 + 1 < nn) { base1[d0 + i0 + 1] = run + p0; plen[d0 + i0 + 1] = (unsigned short)p1; }
    __syncthreads();
    for (int j = threadIdx.x; j < nn; j += 256) {
        unsigned r0 = lrel[j * 3], r1 = lrel[j * 3 + 1], r2 = lrel[j * 3 + 2];
        cnt3[d0 + j] = r0 | (r1 << 10) | (r2 << 20);
    }
    for (int e = estart + threadIdx.x; e < eend; e += 256) {
        unsigned p = staged[e];
        int dloc = p >> 19;
        unsigned src = p & 0x1FFFF;
        unsigned rel = (p >> 17) & 3;
        int slot = atomicAdd(&lcnt[dloc], 1);
        edges2[slot] = (src << 5) | (rel << 28);
        edges1[slot] = (unsigned char)(((unsigned)combo[src] << 2) | rel);
    }
    __syncthreads();
    for (int j = threadIdx.x; j < nn; j += 256) {
        if (lraw[j] & 1) {                 // one dummy pad (rel=3, src=0)
            int slot = lcnt[j];
            edges2[slot] = 3u << 28;
            edges1[slot] = 3;
        }
    }
}

// ---------------------------------------------------------------------------
// K7: conv1 aggregation. Wave per node; halves process alternate edges.
//   AGG1[i][r*32+k] = mean of x1tab[combo(src)][k] over rel-r edges
// ---------------------------------------------------------------------------
__global__ void __launch_bounds__(256) agg1_kernel(
        const unsigned char* __restrict__ edges1, const int* __restrict__ base1,
        const unsigned short* __restrict__ plen, const unsigned* __restrict__ cnt3,
        const float* __restrict__ x1tab, unsigned short* __restrict__ AGG1, int N) {
    __shared__ float tab[64 * 32];
    for (int t = threadIdx.x; t < 64 * 32; t += 256) tab[t] = x1tab[t];
    __syncthreads();
    int i = blockIdx.x * 4 + (threadIdx.x >> 6);
    if (i >= N) return;
    int lane = threadIdx.x & 63;
    int k = lane & 31, half = lane >> 5;
    int s = base1[i], L = plen[i];
    float a0 = 0.f, a1 = 0.f, a2 = 0.f;
    int it = 0;
    for (; it + 4 <= L; it += 4) {
        unsigned wA = edges1[s + it + half];
        unsigned wB = edges1[s + it + 2 + half];
        float vA = tab[(wA >> 2) * 32 + k];
        float vB = tab[(wB >> 2) * 32 + k];
        unsigned rA = wA & 3, rB = wB & 3;
        a0 += (rA == 0) ? vA : 0.f;
        a1 += (rA == 1) ? vA : 0.f;
        a2 += (rA == 2) ? vA : 0.f;
        a0 += (rB == 0) ? vB : 0.f;
        a1 += (rB == 1) ? vB : 0.f;
        a2 += (rB == 2) ? vB : 0.f;
    }
    if (it < L) {
        unsigned wA = edges1[s + it + half];
        float vA = tab[(wA >> 2) * 32 + k];
        unsigned rA = wA & 3;
        a0 += (rA == 0) ? vA : 0.f;
        a1 += (rA == 1) ? vA : 0.f;
        a2 += (rA == 2) ? vA : 0.f;
    }
    a0 += __shfl_xor(a0, 32);
    a1 += __shfl_xor(a1, 32);
    a2 += __shfl_xor(a2, 32);
    if (half == 0) {
        unsigned c3 = cnt3[i];
        unsigned c0 = c3 & 1023, c1 = (c3 >> 10) & 1023, c2 = c3 >> 20;
        AGG1[(size_t)i * 96 + k]      = f2bf(a0 * (c0 ? 1.f / (float)c0 : 0.f));
        AGG1[(size_t)i * 96 + 32 + k] = f2bf(a1 * (c1 ? 1.f / (float)c1 : 0.f));
        AGG1[(size_t)i * 96 + 64 + k] = f2bf(a2 * (c2 ? 1.f / (float)c2 : 0.f));
    }
}

// ---------------------------------------------------------------------------
// K8: conv1 transform. MFMA [16,96]@[96,64] + root-table epilogue -> h1 bf16
// ---------------------------------------------------------------------------
__global__ void __launch_bounds__(256) gemm1_kernel(
        const unsigned short* __restrict__ AGG1, const unsigned short* __restrict__ B1f,
        const float* __restrict__ root1t, const unsigned char* __restrict__ combo,
        unsigned short* __restrict__ h1, int N) {
    int g = blockIdx.x * 4 + (threadIdx.x >> 6);
    int node0 = g * 16;
    if (node0 >= N) return;
    int lane = threadIdx.x & 63;
    int m = lane & 15, kg = lane >> 4;
    short8 a[3];
#pragma unroll
    for (int kt = 0; kt < 3; ++kt)
        a[kt] = *(const short8*)(AGG1 + (size_t)(node0 + m) * 96 + kt * 32 + kg * 8);
#pragma unroll
    for (int nt = 0; nt < 4; ++nt) {
        floatx4 c = {0.f, 0.f, 0.f, 0.f};
#pragma unroll
        for (int kt = 0; kt < 3; ++kt) {
            short8 b = *(const short8*)(B1f + ((nt * 3 + kt) * 64 + lane) * 8);
            c = __builtin_amdgcn_mfma_f32_16x16x32_bf16(a[kt], b, c, 0, 0, 0);
        }
#pragma unroll
        for (int q = 0; q < 4; ++q) {
            int node = node0 + kg * 4 + q;
            if (node < N) {
                float v = c[q] + root1t[(int)combo[node] * 64 + nt * 16 + m];
                v = v > 0.f ? v : 0.f;
                h1[(size_t)node * 64 + nt * 16 + m] = f2bf(v);
            }
        }
    }
}

// ---------------------------------------------------------------------------
// K9: conv2 aggregation, 2 edges per wave-load. Wave per node; half-wave h
// processes edge s+2t+h; each lane loads a DWORD (2 bf16 dims) of h1[src].
// ---------------------------------------------------------------------------
__global__ void __launch_bounds__(256) agg2_kernel(
        const unsigned* __restrict__ edges2, const int* __restrict__ base1,
        const unsigned short* __restrict__ plen, const unsigned* __restrict__ cnt3,
        const unsigned* __restrict__ h1u, unsigned* __restrict__ AGG2u, int N) {
    int i = blockIdx.x * 4 + (threadIdx.x >> 6);
    if (i >= N) return;
    int lane = threadIdx.x & 63;
    int l32 = lane & 31, half = lane >> 5;
    int s = base1[i], L = plen[i];
    float a00 = 0.f, a01 = 0.f, a10 = 0.f, a11 = 0.f, a20 = 0.f, a21 = 0.f;
    int it = 0;
    for (; it + 4 <= L; it += 4) {
        unsigned pA = edges2[s + it + half];
        unsigned pB = edges2[s + it + 2 + half];
        unsigned vA = h1u[(pA & 0x0FFFFFFF) + l32];
        unsigned vB = h1u[(pB & 0x0FFFFFFF) + l32];
        unsigned rA = pA >> 28, rB = pB >> 28;
        float fAl = asf(vA << 16), fAh = asf(vA & 0xFFFF0000u);
        float fBl = asf(vB << 16), fBh = asf(vB & 0xFFFF0000u);
        a00 += (rA == 0) ? fAl : 0.f; a01 += (rA == 0) ? fAh : 0.f;
        a10 += (rA == 1) ? fAl : 0.f; a11 += (rA == 1) ? fAh : 0.f;
        a20 += (rA == 2) ? fAl : 0.f; a21 += (rA == 2) ? fAh : 0.f;
        a00 += (rB == 0) ? fBl : 0.f; a01 += (rB == 0) ? fBh : 0.f;
        a10 += (rB == 1) ? fBl : 0.f; a11 += (rB == 1) ? fBh : 0.f;
        a20 += (rB == 2) ? fBl : 0.f; a21 += (rB == 2) ? fBh : 0.f;
    }
    if (it < L) {
        unsigned pA = edges2[s + it + half];
        unsigned vA = h1u[(pA & 0x0FFFFFFF) + l32];
        unsigned rA = pA >> 28;
        float fAl = asf(vA << 16), fAh = asf(vA & 0xFFFF0000u);
        a00 += (rA == 0) ? fAl : 0.f; a01 += (rA == 0) ? fAh : 0.f;
        a10 += (rA == 1) ? fAl : 0.f; a11 += (rA == 1) ? fAh : 0.f;
        a20 += (rA == 2) ? fAl : 0.f; a21 += (rA == 2) ? fAh : 0.f;
    }
    a00 += __shfl_xor(a00, 32); a01 += __shfl_xor(a01, 32);
    a10 += __shfl_xor(a10, 32); a11 += __shfl_xor(a11, 32);
    a20 += __shfl_xor(a20, 32); a21 += __shfl_xor(a21, 32);
    if (half == 0) {
        unsigned c3 = cnt3[i];
        unsigned c0 = c3 & 1023, c1 = (c3 >> 10) & 1023, c2 = c3 >> 20;
        float s0 = c0 ? 1.f / (float)c0 : 0.f;
        float s1 = c1 ? 1.f / (float)c1 : 0.f;
        float s2 = c2 ? 1.f / (float)c2 : 0.f;
        AGG2u[(size_t)i * 96 + l32]      = (unsigned)f2bf(a00 * s0) | ((unsigned)f2bf(a01 * s0) << 16);
        AGG2u[(size_t)i * 96 + 32 + l32] = (unsigned)f2bf(a10 * s1) | ((unsigned)f2bf(a11 * s1) << 16);
        AGG2u[(size_t)i * 96 + 64 + l32] = (unsigned)f2bf(a20 * s2) | ((unsigned)f2bf(a21 * s2) << 16);
    }
}

// ---------------------------------------------------------------------------
// K10: conv2 transform + fused mean-pool scatter. MFMA [16,256]@[256,64];
// epilogue: relu then atomicAdd into pooled[batch[node]][dim].
// ---------------------------------------------------------------------------
__global__ void __launch_bounds__(256) gemm2_pool(
        const unsigned short* __restrict__ h1, const unsigned short* __restrict__ AGG2,
        const unsigned short* __restrict__ B2f, const float* __restrict__ b2,
        const int* __restrict__ batch, float* __restrict__ pooled, int N) {
    int g = blockIdx.x * 4 + (threadIdx.x >> 6);
    int node0 = g * 16;
    if (node0 >= N) return;
    int lane = threadIdx.x & 63;
    int m = lane & 15, kg = lane >> 4;
    short8 a[8];
#pragma unroll
    for (int kt = 0; kt < 2; ++kt)
        a[kt] = *(const short8*)(h1 + (size_t)(node0 + m) * 64 + kt * 32 + kg * 8);
#pragma unroll
    for (int kt = 2; kt < 8; ++kt)
        a[kt] = *(const short8*)(AGG2 + (size_t)(node0 + m) * 192 + (kt - 2) * 32 + kg * 8);
    int bq[4];
#pragma unroll
    for (int q = 0; q < 4; ++q) {
        int node = node0 + kg * 4 + q;
        bq[q] = batch[node < N ? node : N - 1];
    }
#pragma unroll
    for (int nt = 0; nt < 4; ++nt) {
        floatx4 c = {0.f, 0.f, 0.f, 0.f};
#pragma unroll
        for (int kt = 0; kt < 8; ++kt) {
            short8 b = *(const short8*)(B2f + ((nt * 8 + kt) * 64 + lane) * 8);
            c = __builtin_amdgcn_mfma_f32_16x16x32_bf16(a[kt], b, c, 0, 0, 0);
        }
        float bias = b2[nt * 16 + m];
#pragma unroll
        for (int q = 0; q < 4; ++q) {
            int node = node0 + kg * 4 + q;
            if (node < N) {
                float v = c[q] + bias;
                v = v > 0.f ? v : 0.f;
                atomicAdd(&pooled[bq[q] * 64 + nt * 16 + m], v);
            }
        }
    }
}

// ---------------------------------------------------------------------------
// K11: classifier from pooled sums; counts via sorted-batch binary search.
// ---------------------------------------------------------------------------
__global__ void __launch_bounds__(64) cls_kernel(
        const float* __restrict__ pooled, const int* __restrict__ batch,
        const float* __restrict__ cls_w, const float* __restrict__ cls_b,
        float* __restrict__ out, int N, int G) {
    int g = blockIdx.x, lane = threadIdx.x;
    auto lb = [&](int key) {
        int lo = 0, hi = N;
        while (lo < hi) { int mid = (lo + hi) >> 1; if (batch[mid] < key) lo = mid + 1; else hi = mid; }
        return lo;
    };
    int cnt = lb(g + 1) - lb(g);
    float p = pooled[g * 64 + lane] / (float)(cnt > 0 ? cnt : 1);
    __shared__ float ps[64];
    ps[lane] = p;
    __syncthreads();
    if (lane < 10) {
        float o = cls_b[lane];
#pragma unroll
        for (int j = 0; j < 64; ++j) o = fmaf(ps[j], cls_w[j * 10 + lane], o);
        out[g * 10 + lane] = o;
    }
}

// ---------------------------------------------------------------------------
extern "C" void kernel_launch(void* const* d_in, const int* in_sizes, int n_in,
                              void* d_out, int out_size, void* d_ws, size_t ws_size,
                              hipStream_t stream) {
    const int*   node_x = (const int*)d_in[0];
    const int*   ei     = (const int*)d_in[1];
    const int*   et     = (const int*)d_in[2];
    const int*   batch  = (const int*)d_in[3];
    const float* pre_w  = (const float*)d_in[4];
    const float* pre_b  = (const float*)d_in[5];
    const float* w1     = (const float*)d_in[6];
    const float* root1  = (const float*)d_in[7];
    const float* b1     = (const float*)d_in[8];
    const float* w2     = (const float*)d_in[9];
    const float* root2  = (const float*)d_in[10];
    const float* b2     = (const float*)d_in[11];
    const float* cls_w  = (const float*)d_in[12];
    const float* cls_b  = (const float*)d_in[13];
    float* out = (float*)d_out;

    int N = in_sizes[0] / 2;
    int E = in_sizes[1] / 2;
    int G = out_size / 10;

    int NB = (N + BNODES - 1) >> BSH;
    int chunk = (E + NBLK_A - 1) / NBLK_A;
    int nh = NB * NBLK_A;
    int nscan = (nh + 1023) / 1024;
    int EP = E + NB * BNODES;          // padded edge capacity

    char* ws = (char*)d_ws;
    size_t off_b = 0;
    auto alloc = [&](size_t bytes) {
        void* p = ws + off_b;
        off_b = (off_b + bytes + 255) & ~(size_t)255;
        return p;
    };
    float*          x1tab  = (float*)alloc(64 * 32 * sizeof(float));
    float*          root1t = (float*)alloc(64 * 64 * sizeof(float));
    unsigned short* B1f    = (unsigned short*)alloc(4 * 3 * 64 * 8 * sizeof(short));
    unsigned short* B2f    = (unsigned short*)alloc(4 * 8 * 64 * 8 * sizeof(short));
    unsigned char*  combo  = (unsigned char*)alloc((size_t)N + 64);
    int*            hist   = (int*)alloc((size_t)nh * sizeof(int));
    int*            hoff   = (int*)alloc((size_t)nh * sizeof(int));
    int*            bsums  = (int*)alloc(128 * sizeof(int));
    unsigned*       staged = (unsigned*)alloc((size_t)E * sizeof(unsigned));
    unsigned char*  edges1 = (unsigned char*)alloc((size_t)EP);
    unsigned*       edges2 = (unsigned*)alloc((size_t)EP * sizeof(unsigned));
    int*            base1  = (int*)alloc(((size_t)N + 8) * sizeof(int));
    unsigned short* plen   = (unsigned short*)alloc(((size_t)N + 8) * sizeof(short));
    unsigned*       cnt3   = (unsigned*)alloc((size_t)N * sizeof(unsigned));
    unsigned short* h1     = (unsigned short*)alloc((size_t)(N + 16) * 64 * sizeof(short));
    unsigned short* AGGbuf = (unsigned short*)alloc((size_t)(N + 16) * 192 * sizeof(short));
    float*          pooled = (float*)alloc((size_t)G * 64 * sizeof(float));
    unsigned short* AGG1 = AGGbuf;            // [N+16][96]  (dead before AGG2 written)
    unsigned*       AGG2u = (unsigned*)AGGbuf; // [N+16][96] u32 = [N+16][192] bf16

    build_tables<<<64, 64, 0, stream>>>(pre_w, pre_b, root1, b1, x1tab, root1t);
    prep_B<<<64, 256, 0, stream>>>(w1, root2, w2, B1f, B2f);
    combo_kernel<<<(N + 255) / 256, 256, 0, stream>>>(node_x, combo, N);
    hipMemsetAsync(pooled, 0, (size_t)G * 64 * sizeof(float), stream);

    hist_kernel<<<NBLK_A, 256, 0, stream>>>(ei, hist, E, NB, chunk);
    scan1<<<nscan, 1024, 0, stream>>>(hist, hoff, bsums, nh);
    scan2<<<1, 128, 0, stream>>>(bsums, nscan);
    scan3<<<nscan, 1024, 0, stream>>>(hoff, bsums, nh);
    place_kernel<<<NBLK_A, 256, 0, stream>>>(ei, et, hoff, staged, E, NB, chunk);
    finalize_kernel<<<NB, 256, 0, stream>>>(staged, hoff, combo, edges1, edges2,
                                            base1, plen, cnt3, E, N, NB);

    agg1_kernel<<<(N + 3) / 4, 256, 0, stream>>>(edges1, base1, plen, cnt3, x1tab, AGG1, N);
    gemm1_kernel<<<((N + 15) / 16 + 3) / 4, 256, 0, stream>>>(AGG1, B1f, root1t, combo, h1, N);
    agg2_kernel<<<(N + 3) / 4, 256, 0, stream>>>(edges2, base1, plen, cnt3,
                                                 (const unsigned*)h1, AGG2u, N);
    gemm2_pool<<<((N + 15) / 16 + 3) / 4, 256, 0, stream>>>(h1, (const unsigned short*)AGG2u,
                                                            B2f, b2, batch, pooled, N);
    cls_kernel<<<G, 64, 0, stream>>>(pooled, batch, cls_w, cls_b, out, N, G);
}

// Round 6
// 236.856 us; speedup vs baseline: 1.6127x; 1.1833x over previous
//
#include <hip/hip_runtime.h>

#define NREL 3
#define BSH 9              // 512 nodes per dst bucket
#define BNODES 512
#define NBLK_A 256         // blocks in hist/place passes

typedef __attribute__((ext_vector_type(8))) short short8;
typedef __attribute__((ext_vector_type(4))) float floatx4;

static __device__ inline float bf2f(unsigned short u) {
    union { unsigned int i; float f; } v; v.i = ((unsigned int)u) << 16; return v.f;
}
static __device__ inline unsigned short f2bf(float f) {
    union { float f; unsigned int i; } v; v.f = f;
    unsigned int x = v.i;
    return (unsigned short)((x + 0x7FFF + ((x >> 16) & 1)) >> 16);  // RNE
}
static __device__ inline float asf(unsigned int u) {
    union { unsigned int i; float f; } v; v.i = u; return v.f;
}

// ---------------------------------------------------------------------------
// K1: per-combo tables. x1tab[64][32], root1t[64][64] (= x1@root1 + b1)
// ---------------------------------------------------------------------------
__global__ void build_tables(const float* __restrict__ pre_w, const float* __restrict__ pre_b,
                             const float* __restrict__ root1, const float* __restrict__ b1,
                             float* __restrict__ x1tab, float* __restrict__ root1t) {
    int combo = blockIdx.x, j = threadIdx.x;
    __shared__ float x1s[32];
    int s = combo >> 3, c = combo & 7;
    if (j < 32) {
        float v = pre_w[s * 32 + j] + pre_w[(8 + c) * 32 + j] + pre_b[j];
        v = v > 0.f ? v : 0.f;
        x1s[j] = v;
        x1tab[combo * 32 + j] = v;
    }
    __syncthreads();
    float acc = b1[j];
#pragma unroll
    for (int k = 0; k < 32; ++k) acc = fmaf(x1s[k], root1[k * 64 + j], acc);
    root1t[combo * 64 + j] = acc;
}

// ---------------------------------------------------------------------------
// K2: pre-shuffle weights into MFMA B-fragment layout (bf16).
// ---------------------------------------------------------------------------
__global__ void prep_B(const float* __restrict__ w1, const float* __restrict__ root2,
                       const float* __restrict__ w2,
                       unsigned short* __restrict__ B1f, unsigned short* __restrict__ B2f) {
    int t = blockIdx.x * blockDim.x + threadIdx.x;
    if (t < 4 * 8 * 64 * 8) {
        int i = t & 7, l = (t >> 3) & 63, kt = (t >> 9) & 7, nt = t >> 12;
        int k = kt * 32 + ((l >> 4) * 8) + i;
        int col = nt * 16 + (l & 15);
        float v = (k < 64) ? root2[k * 64 + col] : w2[(k - 64) * 64 + col];
        B2f[t] = f2bf(v);
    }
    if (t < 4 * 3 * 64 * 8) {
        int i = t & 7, l = (t >> 3) & 63;
        int rest = t >> 9;
        int kt = rest % 3, nt = rest / 3;
        int k = kt * 32 + ((l >> 4) * 8) + i;
        int col = nt * 16 + (l & 15);
        B1f[t] = f2bf(w1[k * 64 + col]);
    }
}

// K3: combo[i] as u8
__global__ void combo_kernel(const int* __restrict__ node_x, unsigned char* __restrict__ combo, int N) {
    int i = blockIdx.x * blockDim.x + threadIdx.x;
    if (i < N) combo[i] = (unsigned char)(node_x[2 * i] * 8 + node_x[2 * i + 1]);
}

// ---------------------------------------------------------------------------
// K4 (pass A0): per-block dst-bucket histogram. hist[b*NBLK_A + blk]
// ---------------------------------------------------------------------------
__global__ void __launch_bounds__(256) hist_kernel(const int* __restrict__ ei,
                                                   int* __restrict__ hist, int E, int NB, int chunk) {
    __shared__ int lh[256];
    for (int t = threadIdx.x; t < NB; t += 256) lh[t] = 0;
    __syncthreads();
    int s = blockIdx.x * chunk, e1 = min(E, s + chunk);
    for (int e = s + threadIdx.x; e < e1; e += 256)
        atomicAdd(&lh[ei[E + e] >> BSH], 1);
    __syncthreads();
    for (int b = threadIdx.x; b < NB; b += 256) hist[b * NBLK_A + blockIdx.x] = lh[b];
}

// generic exclusive scan (3 kernels)
__global__ void scan1(const int* __restrict__ in, int* __restrict__ out,
                      int* __restrict__ bsums, int n) {
    __shared__ int s[1024];
    int i = blockIdx.x * 1024 + threadIdx.x;
    int d = (i < n) ? in[i] : 0;
    s[threadIdx.x] = d;
    __syncthreads();
    for (int off = 1; off < 1024; off <<= 1) {
        int v = (threadIdx.x >= off) ? s[threadIdx.x - off] : 0;
        __syncthreads();
        s[threadIdx.x] += v;
        __syncthreads();
    }
    if (i < n) out[i] = s[threadIdx.x] - d;
    if (threadIdx.x == 1023) bsums[blockIdx.x] = s[1023];
}
__global__ void scan2(int* __restrict__ bsums, int nb) {
    __shared__ int s[128];
    int v = (threadIdx.x < nb) ? bsums[threadIdx.x] : 0;
    s[threadIdx.x] = v;
    __syncthreads();
    for (int off = 1; off < 128; off <<= 1) {
        int u = (threadIdx.x >= off) ? s[threadIdx.x - off] : 0;
        __syncthreads();
        s[threadIdx.x] += u;
        __syncthreads();
    }
    if (threadIdx.x < nb) bsums[threadIdx.x] = s[threadIdx.x] - v;
}
__global__ void scan3(int* __restrict__ out, const int* __restrict__ bsums, int n) {
    int i = blockIdx.x * 1024 + threadIdx.x;
    if (i < n) out[i] += bsums[blockIdx.x];
}

// ---------------------------------------------------------------------------
// K5 (pass A1): place edges into dst-buckets. staged = dloc<<19 | rel<<17 | src
// ---------------------------------------------------------------------------
__global__ void __launch_bounds__(256) place_kernel(const int* __restrict__ ei, const int* __restrict__ et,
                                                    const int* __restrict__ off, unsigned* __restrict__ staged,
                                                    int E, int NB, int chunk) {
    __shared__ int lh[256];
    for (int t = threadIdx.x; t < NB; t += 256) lh[t] = 0;
    __syncthreads();
    int s = blockIdx.x * chunk, e1 = min(E, s + chunk);
    for (int e = s + threadIdx.x; e < e1; e += 256) {
        int d = ei[E + e];
        int b = d >> BSH;
        int lr = atomicAdd(&lh[b], 1);
        int pos = off[b * NBLK_A + blockIdx.x] + lr;
        staged[pos] = ((unsigned)(d & (BNODES - 1)) << 19) | ((unsigned)et[e] << 17) | (unsigned)ei[e];
    }
}

// ---------------------------------------------------------------------------
// K6 (pass B): per-bucket finalize into even-padded per-dst CSR.
//   edges2[e] = src*32 | rel<<28      (rel=3 -> dummy)
//   edges1[e] = combo(src)<<2 | rel   (u8)
//   base1[i]  = start of node i's span; plen[i] = padded (even) length
//   cnt3[i]   = packed per-rel true counts (10 bits each)
// ---------------------------------------------------------------------------
__global__ void __launch_bounds__(256) finalize_kernel(
        const unsigned* __restrict__ staged, const int* __restrict__ off,
        const unsigned char* __restrict__ combo,
        unsigned char* __restrict__ edges1, unsigned* __restrict__ edges2,
        int* __restrict__ base1, unsigned short* __restrict__ plen,
        unsigned* __restrict__ cnt3, int E, int N, int NB) {
    __shared__ int lcnt[BNODES];        // raw counts -> placement cursors
    __shared__ int lraw[BNODES];
    __shared__ int lrel[BNODES * 3];
    __shared__ int part[256];
    int blk = blockIdx.x;
    int d0 = blk * BNODES;
    int nn = min(BNODES, N - d0);
    int estart = off[blk * NBLK_A];
    int eend = (blk == NB - 1) ? E : off[(blk + 1) * NBLK_A];
    int ebase = estart + blk * BNODES;  // padded-capacity base
    for (int t = threadIdx.x; t < BNODES; t += 256) lcnt[t] = 0;
    for (int t = threadIdx.x; t < BNODES * 3; t += 256) lrel[t] = 0;
    __syncthreads();
    for (int e = estart + threadIdx.x; e < eend; e += 256) {
        unsigned p = staged[e];
        int dloc = p >> 19;
        atomicAdd(&lcnt[dloc], 1);
        atomicAdd(&lrel[dloc * 3 + ((p >> 17) & 3)], 1);
    }
    __syncthreads();
    // padded exclusive scan (2 nodes per thread)
    int t = threadIdx.x;
    int i0 = t * 2;
    int c0 = lcnt[i0], c1 = lcnt[i0 + 1];
    int p0 = (c0 + 1) & ~1, p1 = (c1 + 1) & ~1;
    int sum = p0 + p1;
    part[t] = sum;
    __syncthreads();
    for (int o = 1; o < 256; o <<= 1) {
        int u = (t >= o) ? part[t - o] : 0;
        __syncthreads();
        part[t] += u;
        __syncthreads();
    }
    int run = ebase + part[t] - sum;
    lraw[i0] = c0; lraw[i0 + 1] = c1;
    lcnt[i0] = run; lcnt[i0 + 1] = run + p0;
    if (i0 < nn)     { base1[d0 + i0] = run;          plen[d0 + i0] = (unsigned short)p0; }
    if (i0 + 1 < nn) { base1[d0 + i0 + 1] = run + p0; plen[d0 + i0 + 1] = (unsigned short)p1; }
    __syncthreads();
    for (int j = threadIdx.x; j < nn; j += 256) {
        unsigned r0 = lrel[j * 3], r1 = lrel[j * 3 + 1], r2 = lrel[j * 3 + 2];
        cnt3[d0 + j] = r0 | (r1 << 10) | (r2 << 20);
    }
    for (int e = estart + threadIdx.x; e < eend; e += 256) {
        unsigned p = staged[e];
        int dloc = p >> 19;
        unsigned src = p & 0x1FFFF;
        unsigned rel = (p >> 17) & 3;
        int slot = atomicAdd(&lcnt[dloc], 1);
        edges2[slot] = (src << 5) | (rel << 28);
        edges1[slot] = (unsigned char)(((unsigned)combo[src] << 2) | rel);
    }
    __syncthreads();
    for (int j = threadIdx.x; j < nn; j += 256) {
        if (lraw[j] & 1) {                 // one dummy pad (rel=3, src=0)
            int slot = lcnt[j];
            edges2[slot] = 3u << 28;
            edges1[slot] = 3;
        }
    }
}

// ---------------------------------------------------------------------------
// K7: conv1 aggregation. Wave per node; halves process alternate edges.
// ---------------------------------------------------------------------------
__global__ void __launch_bounds__(256) agg1_kernel(
        const unsigned char* __restrict__ edges1, const int* __restrict__ base1,
        const unsigned short* __restrict__ plen, const unsigned* __restrict__ cnt3,
        const float* __restrict__ x1tab, unsigned short* __restrict__ AGG1, int N) {
    __shared__ float tab[64 * 32];
    for (int t = threadIdx.x; t < 64 * 32; t += 256) tab[t] = x1tab[t];
    __syncthreads();
    int i = blockIdx.x * 4 + (threadIdx.x >> 6);
    if (i >= N) return;
    int lane = threadIdx.x & 63;
    int k = lane & 31, half = lane >> 5;
    int s = base1[i], L = plen[i];
    float a0 = 0.f, a1 = 0.f, a2 = 0.f;
    int it = 0;
    for (; it + 4 <= L; it += 4) {
        unsigned wA = edges1[s + it + half];
        unsigned wB = edges1[s + it + 2 + half];
        float vA = tab[(wA >> 2) * 32 + k];
        float vB = tab[(wB >> 2) * 32 + k];
        unsigned rA = wA & 3, rB = wB & 3;
        a0 += (rA == 0) ? vA : 0.f;
        a1 += (rA == 1) ? vA : 0.f;
        a2 += (rA == 2) ? vA : 0.f;
        a0 += (rB == 0) ? vB : 0.f;
        a1 += (rB == 1) ? vB : 0.f;
        a2 += (rB == 2) ? vB : 0.f;
    }
    if (it < L) {
        unsigned wA = edges1[s + it + half];
        float vA = tab[(wA >> 2) * 32 + k];
        unsigned rA = wA & 3;
        a0 += (rA == 0) ? vA : 0.f;
        a1 += (rA == 1) ? vA : 0.f;
        a2 += (rA == 2) ? vA : 0.f;
    }
    a0 += __shfl_xor(a0, 32);
    a1 += __shfl_xor(a1, 32);
    a2 += __shfl_xor(a2, 32);
    if (half == 0) {
        unsigned c3 = cnt3[i];
        unsigned c0 = c3 & 1023, c1 = (c3 >> 10) & 1023, c2 = c3 >> 20;
        AGG1[(size_t)i * 96 + k]      = f2bf(a0 * (c0 ? 1.f / (float)c0 : 0.f));
        AGG1[(size_t)i * 96 + 32 + k] = f2bf(a1 * (c1 ? 1.f / (float)c1 : 0.f));
        AGG1[(size_t)i * 96 + 64 + k] = f2bf(a2 * (c2 ? 1.f / (float)c2 : 0.f));
    }
}

// ---------------------------------------------------------------------------
// K8: conv1 transform. MFMA [16,96]@[96,64] + root-table epilogue -> h1 bf16
// ---------------------------------------------------------------------------
__global__ void __launch_bounds__(256) gemm1_kernel(
        const unsigned short* __restrict__ AGG1, const unsigned short* __restrict__ B1f,
        const float* __restrict__ root1t, const unsigned char* __restrict__ combo,
        unsigned short* __restrict__ h1, int N) {
    int g = blockIdx.x * 4 + (threadIdx.x >> 6);
    int node0 = g * 16;
    if (node0 >= N) return;
    int lane = threadIdx.x & 63;
    int m = lane & 15, kg = lane >> 4;
    short8 a[3];
#pragma unroll
    for (int kt = 0; kt < 3; ++kt)
        a[kt] = *(const short8*)(AGG1 + (size_t)(node0 + m) * 96 + kt * 32 + kg * 8);
#pragma unroll
    for (int nt = 0; nt < 4; ++nt) {
        floatx4 c = {0.f, 0.f, 0.f, 0.f};
#pragma unroll
        for (int kt = 0; kt < 3; ++kt) {
            short8 b = *(const short8*)(B1f + ((nt * 3 + kt) * 64 + lane) * 8);
            c = __builtin_amdgcn_mfma_f32_16x16x32_bf16(a[kt], b, c, 0, 0, 0);
        }
#pragma unroll
        for (int q = 0; q < 4; ++q) {
            int node = node0 + kg * 4 + q;
            if (node < N) {
                float v = c[q] + root1t[(int)combo[node] * 64 + nt * 16 + m];
                v = v > 0.f ? v : 0.f;
                h1[(size_t)node * 64 + nt * 16 + m] = f2bf(v);
            }
        }
    }
}

// ---------------------------------------------------------------------------
// K9: conv2 aggregation, 2 edges per wave-load. Wave per node; half-wave h
// processes edge s+2t+h; each lane loads a DWORD (2 bf16 dims) of h1[src].
// ---------------------------------------------------------------------------
__global__ void __launch_bounds__(256) agg2_kernel(
        const unsigned* __restrict__ edges2, const int* __restrict__ base1,
        const unsigned short* __restrict__ plen, const unsigned* __restrict__ cnt3,
        const unsigned* __restrict__ h1u, unsigned* __restrict__ AGG2u, int N) {
    int i = blockIdx.x * 4 + (threadIdx.x >> 6);
    if (i >= N) return;
    int lane = threadIdx.x & 63;
    int l32 = lane & 31, half = lane >> 5;
    int s = base1[i], L = plen[i];
    float a00 = 0.f, a01 = 0.f, a10 = 0.f, a11 = 0.f, a20 = 0.f, a21 = 0.f;
    int it = 0;
    for (; it + 4 <= L; it += 4) {
        unsigned pA = edges2[s + it + half];
        unsigned pB = edges2[s + it + 2 + half];
        unsigned vA = h1u[(pA & 0x0FFFFFFF) + l32];
        unsigned vB = h1u[(pB & 0x0FFFFFFF) + l32];
        unsigned rA = pA >> 28, rB = pB >> 28;
        float fAl = asf(vA << 16), fAh = asf(vA & 0xFFFF0000u);
        float fBl = asf(vB << 16), fBh = asf(vB & 0xFFFF0000u);
        a00 += (rA == 0) ? fAl : 0.f; a01 += (rA == 0) ? fAh : 0.f;
        a10 += (rA == 1) ? fAl : 0.f; a11 += (rA == 1) ? fAh : 0.f;
        a20 += (rA == 2) ? fAl : 0.f; a21 += (rA == 2) ? fAh : 0.f;
        a00 += (rB == 0) ? fBl : 0.f; a01 += (rB == 0) ? fBh : 0.f;
        a10 += (rB == 1) ? fBl : 0.f; a11 += (rB == 1) ? fBh : 0.f;
        a20 += (rB == 2) ? fBl : 0.f; a21 += (rB == 2) ? fBh : 0.f;
    }
    if (it < L) {
        unsigned pA = edges2[s + it + half];
        unsigned vA = h1u[(pA & 0x0FFFFFFF) + l32];
        unsigned rA = pA >> 28;
        float fAl = asf(vA << 16), fAh = asf(vA & 0xFFFF0000u);
        a00 += (rA == 0) ? fAl : 0.f; a01 += (rA == 0) ? fAh : 0.f;
        a10 += (rA == 1) ? fAl : 0.f; a11 += (rA == 1) ? fAh : 0.f;
        a20 += (rA == 2) ? fAl : 0.f; a21 += (rA == 2) ? fAh : 0.f;
    }
    a00 += __shfl_xor(a00, 32); a01 += __shfl_xor(a01, 32);
    a10 += __shfl_xor(a10, 32); a11 += __shfl_xor(a11, 32);
    a20 += __shfl_xor(a20, 32); a21 += __shfl_xor(a21, 32);
    if (half == 0) {
        unsigned c3 = cnt3[i];
        unsigned c0 = c3 & 1023, c1 = (c3 >> 10) & 1023, c2 = c3 >> 20;
        float s0 = c0 ? 1.f / (float)c0 : 0.f;
        float s1 = c1 ? 1.f / (float)c1 : 0.f;
        float s2 = c2 ? 1.f / (float)c2 : 0.f;
        AGG2u[(size_t)i * 96 + l32]      = (unsigned)f2bf(a00 * s0) | ((unsigned)f2bf(a01 * s0) << 16);
        AGG2u[(size_t)i * 96 + 32 + l32] = (unsigned)f2bf(a10 * s1) | ((unsigned)f2bf(a11 * s1) << 16);
        AGG2u[(size_t)i * 96 + 64 + l32] = (unsigned)f2bf(a20 * s2) | ((unsigned)f2bf(a21 * s2) << 16);
    }
}

// ---------------------------------------------------------------------------
// K10: conv2 transform. MFMA [16,256]@[256,64] -> h2 bf16 (relu deferred)
// ---------------------------------------------------------------------------
__global__ void __launch_bounds__(256) gemm2_kernel(
        const unsigned short* __restrict__ h1, const unsigned short* __restrict__ AGG2,
        const unsigned short* __restrict__ B2f, const float* __restrict__ b2,
        unsigned short* __restrict__ h2, int N) {
    int g = blockIdx.x * 4 + (threadIdx.x >> 6);
    int node0 = g * 16;
    if (node0 >= N) return;
    int lane = threadIdx.x & 63;
    int m = lane & 15, kg = lane >> 4;
    short8 a[8];
#pragma unroll
    for (int kt = 0; kt < 2; ++kt)
        a[kt] = *(const short8*)(h1 + (size_t)(node0 + m) * 64 + kt * 32 + kg * 8);
#pragma unroll
    for (int kt = 2; kt < 8; ++kt)
        a[kt] = *(const short8*)(AGG2 + (size_t)(node0 + m) * 192 + (kt - 2) * 32 + kg * 8);
#pragma unroll
    for (int nt = 0; nt < 4; ++nt) {
        floatx4 c = {0.f, 0.f, 0.f, 0.f};
#pragma unroll
        for (int kt = 0; kt < 8; ++kt) {
            short8 b = *(const short8*)(B2f + ((nt * 8 + kt) * 64 + lane) * 8);
            c = __builtin_amdgcn_mfma_f32_16x16x32_bf16(a[kt], b, c, 0, 0, 0);
        }
        float bias = b2[nt * 16 + m];
#pragma unroll
        for (int q = 0; q < 4; ++q) {
            int node = node0 + kg * 4 + q;
            if (node < N)
                h2[(size_t)node * 64 + nt * 16 + m] = f2bf(c[q] + bias);
        }
    }
}

// ---------------------------------------------------------------------------
// K11: mean-pool (sorted batch -> binary search) + classifier; relu folded.
// ---------------------------------------------------------------------------
__global__ void __launch_bounds__(64) pool_cls(
        const unsigned short* __restrict__ h2, const int* __restrict__ batch,
        const float* __restrict__ cls_w, const float* __restrict__ cls_b,
        float* __restrict__ out, int N, int G) {
    int g = blockIdx.x, lane = threadIdx.x;
    auto lb = [&](int key) {
        int lo = 0, hi = N;
        while (lo < hi) { int mid = (lo + hi) >> 1; if (batch[mid] < key) lo = mid + 1; else hi = mid; }
        return lo;
    };
    int start = lb(g), end = lb(g + 1);
    float sum = 0.f;
    for (int i = start; i < end; ++i) {
        float v = bf2f(h2[(size_t)i * 64 + lane]);
        sum += v > 0.f ? v : 0.f;
    }
    int cntn = end - start;
    float pooled = sum / (float)(cntn > 0 ? cntn : 1);
    __shared__ float ps[64];
    ps[lane] = pooled;
    __syncthreads();
    if (lane < 10) {
        float o = cls_b[lane];
#pragma unroll
        for (int j = 0; j < 64; ++j) o = fmaf(ps[j], cls_w[j * 10 + lane], o);
        out[g * 10 + lane] = o;
    }
}

// ---------------------------------------------------------------------------
extern "C" void kernel_launch(void* const* d_in, const int* in_sizes, int n_in,
                              void* d_out, int out_size, void* d_ws, size_t ws_size,
                              hipStream_t stream) {
    const int*   node_x = (const int*)d_in[0];
    const int*   ei     = (const int*)d_in[1];
    const int*   et     = (const int*)d_in[2];
    const int*   batch  = (const int*)d_in[3];
    const float* pre_w  = (const float*)d_in[4];
    const float* pre_b  = (const float*)d_in[5];
    const float* w1     = (const float*)d_in[6];
    const float* root1  = (const float*)d_in[7];
    const float* b1     = (const float*)d_in[8];
    const float* w2     = (const float*)d_in[9];
    const float* root2  = (const float*)d_in[10];
    const float* b2     = (const float*)d_in[11];
    const float* cls_w  = (const float*)d_in[12];
    const float* cls_b  = (const float*)d_in[13];
    float* out = (float*)d_out;

    int N = in_sizes[0] / 2;
    int E = in_sizes[1] / 2;
    int G = out_size / 10;

    int NB = (N + BNODES - 1) >> BSH;
    int chunk = (E + NBLK_A - 1) / NBLK_A;
    int nh = NB * NBLK_A;
    int nscan = (nh + 1023) / 1024;
    int EP = E + NB * BNODES;          // padded edge capacity

    char* ws = (char*)d_ws;
    size_t off_b = 0;
    auto alloc = [&](size_t bytes) {
        void* p = ws + off_b;
        off_b = (off_b + bytes + 255) & ~(size_t)255;
        return p;
    };
    float*          x1tab  = (float*)alloc(64 * 32 * sizeof(float));
    float*          root1t = (float*)alloc(64 * 64 * sizeof(float));
    unsigned short* B1f    = (unsigned short*)alloc(4 * 3 * 64 * 8 * sizeof(short));
    unsigned short* B2f    = (unsigned short*)alloc(4 * 8 * 64 * 8 * sizeof(short));
    unsigned char*  combo  = (unsigned char*)alloc((size_t)N + 64);
    int*            hist   = (int*)alloc((size_t)nh * sizeof(int));
    int*            hoff   = (int*)alloc((size_t)nh * sizeof(int));
    int*            bsums  = (int*)alloc(128 * sizeof(int));
    unsigned*       staged = (unsigned*)alloc((size_t)E * sizeof(unsigned));
    unsigned char*  edges1 = (unsigned char*)alloc((size_t)EP);
    unsigned*       edges2 = (unsigned*)alloc((size_t)EP * sizeof(unsigned));
    int*            base1  = (int*)alloc(((size_t)N + 8) * sizeof(int));
    unsigned short* plen   = (unsigned short*)alloc(((size_t)N + 8) * sizeof(short));
    unsigned*       cnt3   = (unsigned*)alloc((size_t)N * sizeof(unsigned));
    unsigned short* h1     = (unsigned short*)alloc((size_t)(N + 16) * 64 * sizeof(short));
    unsigned short* h2     = (unsigned short*)alloc((size_t)(N + 16) * 64 * sizeof(short));
    unsigned short* AGGbuf = (unsigned short*)alloc((size_t)(N + 16) * 192 * sizeof(short));
    unsigned short* AGG1 = AGGbuf;             // [N+16][96]  (dead before AGG2 written)
    unsigned*       AGG2u = (unsigned*)AGGbuf; // [N+16][96] u32 = [N+16][192] bf16

    build_tables<<<64, 64, 0, stream>>>(pre_w, pre_b, root1, b1, x1tab, root1t);
    prep_B<<<64, 256, 0, stream>>>(w1, root2, w2, B1f, B2f);
    combo_kernel<<<(N + 255) / 256, 256, 0, stream>>>(node_x, combo, N);

    hist_kernel<<<NBLK_A, 256, 0, stream>>>(ei, hist, E, NB, chunk);
    scan1<<<nscan, 1024, 0, stream>>>(hist, hoff, bsums, nh);
    scan2<<<1, 128, 0, stream>>>(bsums, nscan);
    scan3<<<nscan, 1024, 0, stream>>>(hoff, bsums, nh);
    place_kernel<<<NBLK_A, 256, 0, stream>>>(ei, et, hoff, staged, E, NB, chunk);
    finalize_kernel<<<NB, 256, 0, stream>>>(staged, hoff, combo, edges1, edges2,
                                            base1, plen, cnt3, E, N, NB);

    agg1_kernel<<<(N + 3) / 4, 256, 0, stream>>>(edges1, base1, plen, cnt3, x1tab, AGG1, N);
    gemm1_kernel<<<((N + 15) / 16 + 3) / 4, 256, 0, stream>>>(AGG1, B1f, root1t, combo, h1, N);
    agg2_kernel<<<(N + 3) / 4, 256, 0, stream>>>(edges2, base1, plen, cnt3,
                                                 (const unsigned*)h1, AGG2u, N);
    gemm2_kernel<<<((N + 15) / 16 + 3) / 4, 256, 0, stream>>>(h1, (const unsigned short*)AGG2u,
                                                              B2f, b2, h2, N);
    pool_cls<<<G, 64, 0, stream>>>(h2, batch, cls_w, cls_b, out, N, G);
}